// Round 1
// baseline (423.422 us; speedup 1.0000x reference)
//
#include <hip/hip_runtime.h>

// Problem dims
#define S_DIM 128
#define N_DIM 256
#define H_DIM 1024
#define E_DIM 512
#define V_DIM 32000
#define KE_DIM 1024
#define CIN 2560   // H + E + H  (A2 = [ctx | emb_x | h0])
#define G4 4096    // 4*H

typedef unsigned short u16;
typedef __bf16 bf16x8 __attribute__((ext_vector_type(8)));
typedef float  f32x4  __attribute__((ext_vector_type(4)));

union U16x8 { uint4 u; bf16x8 b; };

// f32 -> bf16 RNE
__device__ __forceinline__ unsigned f2bf(float x) {
  unsigned u = __float_as_uint(x);
  return (u + 0x7FFFu + ((u >> 16) & 1u)) >> 16;
}
__device__ __forceinline__ unsigned pk2(float a, float b) {
  return f2bf(a) | (f2bf(b) << 16);
}

__device__ __forceinline__ bf16x8 frag_from_global(const u16* p) {
  U16x8 t; t.u = *(const uint4*)p; return t.b;
}
__device__ __forceinline__ bf16x8 frag_from_lds(const u16* base, int byteoff) {
  U16x8 t; t.u = *(const uint4*)((const char*)base + byteoff); return t.b;
}

// XOR-swizzled LDS addressing: 16B chunks, chunk' = chunk ^ (row&7).
// Guarantees <=2-way dword-phase bank conflicts for both row-parallel frag
// reads and staging writes (2-way is free, m136).
__device__ __forceinline__ int loff64(int row, int k) {   // 64-col tile (128 B/row)
  return row * 128 + ((((k >> 3) ^ (row & 7)) << 4) | ((k & 7) << 1));
}
__device__ __forceinline__ int loff128(int row, int k) {  // 128-col tile (256 B/row)
  return row * 256 + ((((k >> 3) ^ (row & 7)) << 4) | ((k & 7) << 1));
}

__device__ __forceinline__ f32x4 mfma16(bf16x8 a, bf16x8 b, f32x4 c) {
  return __builtin_amdgcn_mfma_f32_16x16x32_bf16(a, b, c, 0, 0, 0);
}

// ---------------------------------------------------------------------------
// Kernel 1: per-n online-softmax attention over s, ctx = sum_s a[s]*enc[s,n,:]
// Single streaming pass over encoder_states (128 MB read exactly once).
// Epilogue also assembles A2 = [bf16(ctx) | bf16(emb[input[n]]) | bf16(h0[n])].
// ---------------------------------------------------------------------------
__global__ __launch_bounds__(256) void k1_attn(
    const float* __restrict__ enc, const float* __restrict__ hid,
    const float* __restrict__ Wen, const float* __restrict__ ben,
    const int* __restrict__ inp, const float* __restrict__ emb,
    u16* __restrict__ A2)
{
  __shared__ float s_acc[4][H_DIM];   // 16 KB
  __shared__ float s_ml[8];
  const int n = blockIdx.x;
  const int t = threadIdx.x;
  const int wave = t >> 6, lane = t & 63;

  // W_energy row K-1: [0:H) multiplies hidden, [H:2H) multiplies encoder
  const float* Wrow = Wen + (KE_DIM - 1) * (2 * H_DIM);
  float4 we[4];
  #pragma unroll
  for (int ks = 0; ks < 4; ++ks)
    we[ks] = *(const float4*)(Wrow + H_DIM + ks * 256 + lane * 4);

  // hidden-part dot (s-invariant), computed redundantly per wave
  float hd = 0.f;
  #pragma unroll
  for (int ks = 0; ks < 4; ++ks) {
    float4 wh = *(const float4*)(Wrow + ks * 256 + lane * 4);
    float4 hv = *(const float4*)(hid + n * H_DIM + ks * 256 + lane * 4);
    hd += wh.x * hv.x + wh.y * hv.y + wh.z * hv.z + wh.w * hv.w;
  }
  #pragma unroll
  for (int off = 32; off > 0; off >>= 1) hd += __shfl_xor(hd, off, 64);
  const float ebase = hd + ben[KE_DIM - 1];

  // online softmax state (per wave; waves own s = wave, wave+4, ...)
  float m = -INFINITY, l = 0.f;
  float4 acc[4];
  #pragma unroll
  for (int ks = 0; ks < 4; ++ks) acc[ks] = make_float4(0.f, 0.f, 0.f, 0.f);

  const long rstride = 4L * N_DIM * H_DIM;
  const float* p = enc + ((long)wave * N_DIM + n) * H_DIM + lane * 4;
  float4 cur[4];
  #pragma unroll
  for (int ks = 0; ks < 4; ++ks) cur[ks] = *(const float4*)(p + ks * 256);

  for (int s = wave; s < S_DIM; s += 4) {
    float4 nxt[4];
    const float* pn = p + rstride;
    const bool has = (s + 4 < S_DIM);
    if (has) {   // prefetch next row to hide HBM latency
      #pragma unroll
      for (int ks = 0; ks < 4; ++ks) nxt[ks] = *(const float4*)(pn + ks * 256);
    }
    float d = 0.f;
    #pragma unroll
    for (int ks = 0; ks < 4; ++ks)
      d += we[ks].x * cur[ks].x + we[ks].y * cur[ks].y +
           we[ks].z * cur[ks].z + we[ks].w * cur[ks].w;
    #pragma unroll
    for (int off = 32; off > 0; off >>= 1) d += __shfl_xor(d, off, 64);
    const float e  = fmaxf(ebase + d, 0.f);          // ReLU
    const float nm = fmaxf(m, e);
    const float sc = __expf(m - nm);                 // 0 on first iter (m=-inf)
    const float pe = __expf(e - nm);
    l = l * sc + pe;
    #pragma unroll
    for (int ks = 0; ks < 4; ++ks) {
      acc[ks].x = acc[ks].x * sc + pe * cur[ks].x;
      acc[ks].y = acc[ks].y * sc + pe * cur[ks].y;
      acc[ks].z = acc[ks].z * sc + pe * cur[ks].z;
      acc[ks].w = acc[ks].w * sc + pe * cur[ks].w;
    }
    m = nm;
    if (has) {
      #pragma unroll
      for (int ks = 0; ks < 4; ++ks) cur[ks] = nxt[ks];
    }
    p = pn;
  }

  // merge the 4 per-wave states
  #pragma unroll
  for (int ks = 0; ks < 4; ++ks)
    *(float4*)&s_acc[wave][ks * 256 + lane * 4] = acc[ks];
  if (lane == 0) { s_ml[wave] = m; s_ml[4 + wave] = l; }
  __syncthreads();

  const float M = fmaxf(fmaxf(s_ml[0], s_ml[1]), fmaxf(s_ml[2], s_ml[3]));
  const float f0 = __expf(s_ml[0] - M), f1 = __expf(s_ml[1] - M);
  const float f2 = __expf(s_ml[2] - M), f3 = __expf(s_ml[3] - M);
  const float L = s_ml[4] * f0 + s_ml[5] * f1 + s_ml[6] * f2 + s_ml[7] * f3;
  const float invL = 1.0f / L;
  {
    const int e0 = t * 4;
    float v0 = (s_acc[0][e0+0]*f0 + s_acc[1][e0+0]*f1 + s_acc[2][e0+0]*f2 + s_acc[3][e0+0]*f3) * invL;
    float v1 = (s_acc[0][e0+1]*f0 + s_acc[1][e0+1]*f1 + s_acc[2][e0+1]*f2 + s_acc[3][e0+1]*f3) * invL;
    float v2 = (s_acc[0][e0+2]*f0 + s_acc[1][e0+2]*f1 + s_acc[2][e0+2]*f2 + s_acc[3][e0+2]*f3) * invL;
    float v3 = (s_acc[0][e0+3]*f0 + s_acc[1][e0+3]*f1 + s_acc[2][e0+3]*f2 + s_acc[3][e0+3]*f3) * invL;
    uint2 pk; pk.x = pk2(v0, v1); pk.y = pk2(v2, v3);
    *(uint2*)&A2[(long)n * CIN + e0] = pk;
  }

  // A2 tail: emb gather (cols 1024..1535) then h0 copy (cols 1536..2559)
  const int idx = inp[n];
  for (int j = t; j < E_DIM + H_DIM; j += 256) {
    float v = (j < E_DIM) ? emb[(long)idx * E_DIM + j]
                          : hid[n * H_DIM + (j - E_DIM)];
    A2[(long)n * CIN + H_DIM + j] = (u16)f2bf(v);
  }
}

// ---------------------------------------------------------------------------
// Kernel 2: gates = A2 @ [W_ih | W_hh]^T + (b_ih + b_hh).   M=256,N=4096,K=2560
// BM=256 (full M: weights read exactly once), BN=16, BK=128, grid=256 blocks.
// A-frags read directly from L2-resident A2; B staged f32->bf16 through LDS.
// ---------------------------------------------------------------------------
__global__ __launch_bounds__(256) void k2_gates(
    const u16* __restrict__ A2, const float* __restrict__ Wih,
    const float* __restrict__ bih, const float* __restrict__ Whh,
    const float* __restrict__ bhh, float* __restrict__ gates)
{
  __shared__ u16 Blds[16 * 128];   // 4 KB
  const int t = threadIdx.x;
  const int wave = t >> 6, lane = t & 63;
  const int quad = lane >> 4, l15 = lane & 15;
  const int j0 = blockIdx.x * 16;
  const int br = t >> 4;           // 0..15  (B row within tile)
  const int bk = (t & 15) * 8;     // 0..120 (k offset within tile)

  f32x4 acc[4];
  #pragma unroll
  for (int mt = 0; mt < 4; ++mt) acc[mt] = (f32x4){0.f, 0.f, 0.f, 0.f};

  // unified B row j = [W_ih[j,0:1536] | W_hh[j,0:1024]]; 1536 = 12*128 (clean tiles)
  const float* s0 = Wih + (long)(j0 + br) * 1536 + bk;  // k-tile 0 source
  float4 v0 = *(const float4*)s0;
  float4 v1 = *(const float4*)(s0 + 4);

  for (int kt = 0; kt < 20; ++kt) {
    const int k0 = kt * 128;
    uint4 pk;
    pk.x = pk2(v0.x, v0.y); pk.y = pk2(v0.z, v0.w);
    pk.z = pk2(v1.x, v1.y); pk.w = pk2(v1.z, v1.w);
    *(uint4*)((char*)Blds + loff128(br, bk)) = pk;
    if (kt + 1 < 20) {           // register prefetch of next B tile
      const int kn = k0 + 128 + bk;
      const float* sn = (kn < 1536) ? (Wih + (long)(j0 + br) * 1536 + kn)
                                    : (Whh + (long)(j0 + br) * 1024 + (kn - 1536));
      v0 = *(const float4*)sn;
      v1 = *(const float4*)(sn + 4);
    }
    __syncthreads();
    #pragma unroll
    for (int kstep = 0; kstep < 4; ++kstep) {
      const int kl = kstep * 32 + quad * 8;
      const bf16x8 bfrag = frag_from_lds(Blds, loff128(l15, kl));
      #pragma unroll
      for (int mt = 0; mt < 4; ++mt) {
        const int row = wave * 64 + mt * 16 + l15;
        const bf16x8 afrag = frag_from_global(A2 + (long)row * CIN + k0 + kl);
        acc[mt] = mfma16(afrag, bfrag, acc[mt]);
      }
    }
    __syncthreads();
  }

  const float bias = bih[j0 + l15] + bhh[j0 + l15];
  #pragma unroll
  for (int mt = 0; mt < 4; ++mt) {
    #pragma unroll
    for (int r = 0; r < 4; ++r) {
      const int row = wave * 64 + mt * 16 + quad * 4 + r;   // C/D: row=quad*4+reg
      gates[(long)row * G4 + j0 + l15] = acc[mt][r] + bias;
    }
  }
}

// ---------------------------------------------------------------------------
// Kernel 2b: LSTM pointwise (PyTorch gate order i,f,g,o), writes h1/c1 (f32)
// and h1 in bf16 for the fc GEMM.
// ---------------------------------------------------------------------------
__global__ __launch_bounds__(256) void k2b_lstm(
    const float* __restrict__ gates, const float* __restrict__ cell,
    float* __restrict__ h1, float* __restrict__ c1, u16* __restrict__ h1b)
{
  const int i = blockIdx.x * 256 + threadIdx.x;   // 0..262143
  const int n = i >> 10, h = i & 1023;
  const float* g = gates + (long)n * G4 + h;
  const float gi = g[0], gf = g[1024], gg = g[2048], go = g[3072];
  const float si = 1.f / (1.f + __expf(-gi));
  const float sf = 1.f / (1.f + __expf(-gf));
  const float so = 1.f / (1.f + __expf(-go));
  const float tg = tanhf(gg);
  const float cv = sf * cell[i] + si * tg;
  const float hv = so * tanhf(cv);
  c1[i] = cv;
  h1[i] = hv;
  h1b[i] = (u16)f2bf(hv);
}

// ---------------------------------------------------------------------------
// Kernel 3: predictions = h1 @ W_fc^T + b_fc.   M=256, N=32000, K=1024.
// BM=256 (full M: W_fc's 131 MB read exactly once), BN=64, BK=64, grid=500.
// Memory-bound target ~21 us.
// ---------------------------------------------------------------------------
__global__ __launch_bounds__(256) void k3_fc(
    const u16* __restrict__ h1b, const float* __restrict__ Wfc,
    const float* __restrict__ bfc, float* __restrict__ out)
{
  __shared__ u16 Blds[64 * 64];    // 8 KB
  const int t = threadIdx.x;
  const int wave = t >> 6, lane = t & 63;
  const int quad = lane >> 4, l15 = lane & 15;
  const int j0 = blockIdx.x * 64;
  const int br = t >> 2;           // 0..63
  const int bk = (t & 3) * 16;     // 0,16,32,48
  const float* bsrc = Wfc + (long)(j0 + br) * 1024 + bk;

  f32x4 acc[4][4];
  #pragma unroll
  for (int mt = 0; mt < 4; ++mt)
    #pragma unroll
    for (int nt = 0; nt < 4; ++nt) acc[mt][nt] = (f32x4){0.f, 0.f, 0.f, 0.f};

  float4 v0 = *(const float4*)(bsrc);
  float4 v1 = *(const float4*)(bsrc + 4);
  float4 v2 = *(const float4*)(bsrc + 8);
  float4 v3 = *(const float4*)(bsrc + 12);

  for (int kt = 0; kt < 16; ++kt) {
    const int k0 = kt * 64;
    uint4 pa, pb;
    pa.x = pk2(v0.x, v0.y); pa.y = pk2(v0.z, v0.w);
    pa.z = pk2(v1.x, v1.y); pa.w = pk2(v1.z, v1.w);
    pb.x = pk2(v2.x, v2.y); pb.y = pk2(v2.z, v2.w);
    pb.z = pk2(v3.x, v3.y); pb.w = pk2(v3.z, v3.w);
    *(uint4*)((char*)Blds + loff64(br, bk)) = pa;
    *(uint4*)((char*)Blds + loff64(br, bk + 8)) = pb;
    if (kt + 1 < 16) {           // register prefetch of next W_fc tile
      const float* sn = bsrc + (k0 + 64);
      v0 = *(const float4*)(sn);
      v1 = *(const float4*)(sn + 4);
      v2 = *(const float4*)(sn + 8);
      v3 = *(const float4*)(sn + 12);
    }
    __syncthreads();
    #pragma unroll
    for (int kstep = 0; kstep < 2; ++kstep) {
      const int kl = kstep * 32 + quad * 8;
      bf16x8 bfrag[4], afrag[4];
      #pragma unroll
      for (int nt = 0; nt < 4; ++nt)
        bfrag[nt] = frag_from_lds(Blds, loff64(nt * 16 + l15, kl));
      #pragma unroll
      for (int mt = 0; mt < 4; ++mt)
        afrag[mt] = frag_from_global(h1b + (long)(wave * 64 + mt * 16 + l15) * 1024 + k0 + kl);
      #pragma unroll
      for (int mt = 0; mt < 4; ++mt)
        #pragma unroll
        for (int nt = 0; nt < 4; ++nt)
          acc[mt][nt] = mfma16(afrag[mt], bfrag[nt], acc[mt][nt]);
    }
    __syncthreads();
  }

  #pragma unroll
  for (int nt = 0; nt < 4; ++nt) {
    const float bv = bfc[j0 + nt * 16 + l15];
    #pragma unroll
    for (int mt = 0; mt < 4; ++mt) {
      #pragma unroll
      for (int r = 0; r < 4; ++r) {
        const int row = wave * 64 + mt * 16 + quad * 4 + r;
        out[(long)row * V_DIM + j0 + nt * 16 + l15] = acc[mt][nt][r] + bv;
      }
    }
  }
}

// ---------------------------------------------------------------------------
extern "C" void kernel_launch(void* const* d_in, const int* in_sizes, int n_in,
                              void* d_out, int out_size, void* d_ws, size_t ws_size,
                              hipStream_t stream) {
  const int*   inp  = (const int*)  d_in[0];
  const float* enc  = (const float*)d_in[1];
  const float* hid  = (const float*)d_in[2];
  const float* cell = (const float*)d_in[3];
  const float* emb  = (const float*)d_in[4];
  const float* Wen  = (const float*)d_in[5];
  const float* ben  = (const float*)d_in[6];
  const float* Wih  = (const float*)d_in[7];
  const float* bih  = (const float*)d_in[8];
  const float* Whh  = (const float*)d_in[9];
  const float* bhh  = (const float*)d_in[10];
  const float* Wfc  = (const float*)d_in[11];
  const float* bfc  = (const float*)d_in[12];

  float* out  = (float*)d_out;
  float* pred = out;                              // [256, 32000]
  float* h1   = out + (long)N_DIM * V_DIM;        // [1, 256, 1024]
  float* c1   = h1 + (long)N_DIM * H_DIM;         // [1, 256, 1024]

  char* ws = (char*)d_ws;
  u16*   A2    = (u16*)ws;                                   // 256*2560*2 = 1,310,720 B
  float* gates = (float*)(ws + 1310720);                     // 256*4096*4 = 4,194,304 B
  u16*   h1b   = (u16*)(ws + 1310720 + 4194304);             // 256*1024*2 =   524,288 B

  k1_attn <<<N_DIM,            256, 0, stream>>>(enc, hid, Wen, ben, inp, emb, A2);
  k2_gates<<<G4 / 16,          256, 0, stream>>>(A2, Wih, bih, Whh, bhh, gates);
  k2b_lstm<<<(N_DIM*H_DIM)/256,256, 0, stream>>>(gates, cell, h1, c1, h1b);
  k3_fc   <<<V_DIM / 64,       256, 0, stream>>>(h1b, Wfc, bfc, pred);
}